// Round 1
// baseline (241.621 us; speedup 1.0000x reference)
//
#include <hip/hip_runtime.h>

// NMS3D (4,4,32,256,256) fp32, strict 26-neighbor max.
// R7: d-rolling persistent blocks with a 4-slot LDS plane ring.
// R6 analysis: kernel slice (~65us of the 226us bench; the other ~160us is two
// harness re-poison fills) was HBM-bound on its OWN amplified traffic:
// 6-plane/4-output staging = 1.875x read amp (240 MiB read + 128 write -> ~58us
// roofline, ~65 observed). Fix: each block owns (bc, 8 h-rows, 16-plane d-range)
// and walks d, keeping a ring of 4 staged planes (4 x 10 rows x 1 KiB = 40 KiB).
// Per step: DMA-prefetch plane d+2 into the retiring slot (issued BEFORE the
// ds_reads so it overlaps compute; drained by the end-of-step barrier), compute
// output plane d (2 rows/wave), barrier.
//   read amp: d 19/16 x h 10/8 = 1.48  (was 1.875) -> 190 MiB read
//   LDS 40 KiB -> 4 blocks/CU (was 2), DMA overlaps compute in-block.
// Staging stays fire-and-forget global_load_lds DMA (R1-R5 lesson: any
// register-resident pipeline gets de-pipelined by the compiler).

typedef float v4f __attribute__((ext_vector_type(4)));

constexpr int W  = 256;
constexpr int H  = 256;
constexpr int D  = 32;
constexpr int SH = W;
constexpr int SD = W * H;
constexpr int HC = 8;               // h rows per block
constexpr int NR = HC + 2;          // 10 staged rows per plane
constexpr int NSLOT = 4;            // plane ring slots
constexpr int BC = 16;              // B*CH
constexpr int HG = H / HC;          // 32
constexpr int SPLIT = 2;            // d-range halves
constexpr int DR = D / SPLIT;       // 16 output planes per block
constexpr int PLW = NR * W;         // floats per plane slot

__device__ __forceinline__ v4f vmax4(v4f a, v4f b) {
    return (v4f){fmaxf(a.x, b.x), fmaxf(a.y, b.y), fmaxf(a.z, b.z), fmaxf(a.w, b.w)};
}

// Stage the 10 halo'd rows of logical plane p into ring slot p&3.
// Wave w stages rows {w, w+4} and (w<2) ? {w+8}. Row base is wave-uniform;
// lane i's 16B land at base + 16*i -> exact row-major row (DMA constraint).
__device__ __forceinline__ void stage_plane(const float* __restrict__ vol,
                                            float* lds, int p, int h0,
                                            int wv, int lane) {
    const int pc = p < 0 ? 0 : (p > D - 1 ? D - 1 : p);
    float* dst = lds + (p & 3) * PLW;
    const float* src = vol + pc * SD + (lane << 2);
    {
        int hh = h0 - 1 + wv; hh = hh < 0 ? 0 : hh;          // wv<=3 -> no hi clamp
        __builtin_amdgcn_global_load_lds(
            (const __attribute__((address_space(1))) unsigned int*)(src + hh * SH),
            (__attribute__((address_space(3))) unsigned int*)(dst + wv * W), 16, 0, 0);
    }
    {
        const int hh = h0 - 1 + wv + 4;                      // always in 3..255+? no: h0<=248 -> <=255
        __builtin_amdgcn_global_load_lds(
            (const __attribute__((address_space(1))) unsigned int*)(src + hh * SH),
            (__attribute__((address_space(3))) unsigned int*)(dst + (wv + 4) * W), 16, 0, 0);
    }
    if (wv < 2) {
        int hh = h0 - 1 + wv + 8; hh = hh > H - 1 ? H - 1 : hh;
        __builtin_amdgcn_global_load_lds(
            (const __attribute__((address_space(1))) unsigned int*)(src + hh * SH),
            (__attribute__((address_space(3))) unsigned int*)(dst + (wv + 8) * W), 16, 0, 0);
    }
}

// One output row from its 9 staged rows (3 h-rows x 3 planes). Verified math
// from R6 (absmax 0.0): separable vertical max, shuffles for w-edges.
__device__ __forceinline__ v4f nms_row(v4f m0, v4f m1, v4f m2,
                                       v4f c0, v4f c1, v4f c2,
                                       v4f p0, v4f p1, v4f p2,
                                       bool valid, int lane) {
    const v4f a3m = vmax4(vmax4(m0, m1), m2);   // plane d-1, all 3 rows
    const v4f a3p = vmax4(vmax4(p0, p1), p2);   // plane d+1, all 3 rows
    const v4f a20 = vmax4(c0, c2);              // plane d, h +- 1
    const v4f v8  = vmax4(vmax4(a3m, a3p), a20);
    const v4f c   = c1;

    const float l8 = __shfl_up(v8.w, 1);     // lane0 garbage, masked below
    const float r8 = __shfl_down(v8.x, 1);   // lane63 garbage, masked below
    const float lc = __shfl_up(c.w, 1);
    const float rc = __shfl_down(c.x, 1);

    float n0 = fmaxf(fmaxf(l8,   v8.x), v8.y);
    float n1 = fmaxf(fmaxf(v8.x, v8.y), v8.z);
    float n2 = fmaxf(fmaxf(v8.y, v8.z), v8.w);
    float n3 = fmaxf(fmaxf(v8.z, v8.w), r8);
    n0 = fmaxf(n0, fmaxf(lc,  c.y));
    n1 = fmaxf(n1, fmaxf(c.x, c.z));
    n2 = fmaxf(n2, fmaxf(c.y, c.w));
    n3 = fmaxf(n3, fmaxf(c.z, rc));

    v4f o;
    o.x = (valid && lane > 0  && c.x > n0) ? c.x : 0.f;
    o.y = (valid && c.y > n1) ? c.y : 0.f;
    o.z = (valid && c.z > n2) ? c.z : 0.f;
    o.w = (valid && lane < 63 && c.w > n3) ? c.w : 0.f;
    return o;
}

__global__ __launch_bounds__(256, 4) void nms3d_kernel(const float* __restrict__ x,
                                                       float* __restrict__ out) {
    __shared__ float lds[NSLOT * PLW];   // 40 KiB -> 4 blocks/CU

    const int blk  = blockIdx.x;
    const int wv   = threadIdx.x >> 6;   // 0..3
    const int lane = threadIdx.x & 63;
    const int hc   = blk & (HG - 1);           // fastest: h-neighbors share halo rows in L2/L3
    const int half = (blk >> 5) & (SPLIT - 1);
    const int bc   = blk >> 6;
    const int d0   = half * DR;
    const int h0   = hc * HC;

    const float* vol  = x   + bc * (D * SD);
    float*       ovol = out + bc * (D * SD);

    // ---- prologue: stage planes d0-1, d0, d0+1 (slots (d0-1..d0+1)&3) ----
    stage_plane(vol, lds, d0 - 1, h0, wv, lane);
    stage_plane(vol, lds, d0,     h0, wv, lane);
    stage_plane(vol, lds, d0 + 1, h0, wv, lane);
    __syncthreads();   // vmcnt drain + barrier: all 3 planes resident

    const int i0 = wv * 2;               // this wave's two output rows (i0, i0+1)
    const int h  = h0 + i0;
    const bool hv0 = (h > 0) && (h < H - 1);        // wave-uniform
    const bool hv1 = (h + 1 < H - 1);               // h+1 > 0 always

    #pragma unroll 1
    for (int d = d0; d < d0 + DR; ++d) {
        // prefetch plane d+2 into the slot holding d-2 (retired after iter d-1's
        // barrier). Issued first so the DMA overlaps this step's compute; the
        // end-of-step barrier's vmcnt(0) drains it before iter d+1 reads it.
        stage_plane(vol, lds, d + 2, h0, wv, lane);

        const bool dv = (d > 0) && (d < D - 1);
        const float* Lm = lds + ((d - 1) & 3) * PLW + i0 * W + (lane << 2);
        const float* L0 = lds + ( d      & 3) * PLW + i0 * W + (lane << 2);
        const float* Lp = lds + ((d + 1) & 3) * PLW + i0 * W + (lane << 2);

        // rows i0..i0+3 of each plane feed output rows i0, i0+1
        const v4f m0 = *(const v4f*)(Lm + 0 * W), m1 = *(const v4f*)(Lm + 1 * W);
        const v4f m2 = *(const v4f*)(Lm + 2 * W), m3 = *(const v4f*)(Lm + 3 * W);
        const v4f c0 = *(const v4f*)(L0 + 0 * W), c1 = *(const v4f*)(L0 + 1 * W);
        const v4f c2 = *(const v4f*)(L0 + 2 * W), c3 = *(const v4f*)(L0 + 3 * W);
        const v4f p0 = *(const v4f*)(Lp + 0 * W), p1 = *(const v4f*)(Lp + 1 * W);
        const v4f p2 = *(const v4f*)(Lp + 2 * W), p3 = *(const v4f*)(Lp + 3 * W);

        float* orow = ovol + d * SD + h * SH + (lane << 2);
        const v4f o0 = nms_row(m0, m1, m2, c0, c1, c2, p0, p1, p2, hv0 && dv, lane);
        __builtin_nontemporal_store(o0, (v4f*)orow);
        const v4f o1 = nms_row(m1, m2, m3, c1, c2, c3, p1, p2, p3, hv1 && dv, lane);
        __builtin_nontemporal_store(o1, (v4f*)(orow + SH));

        __syncthreads();   // drains DMA for d+2; retires slot (d-1)&3 for reuse
    }
}

extern "C" void kernel_launch(void* const* d_in, const int* in_sizes, int n_in,
                              void* d_out, int out_size, void* d_ws, size_t ws_size,
                              hipStream_t stream) {
    const float* x = (const float*)d_in[0];
    float* out = (float*)d_out;
    // blocks = BC * HG * SPLIT = 16*32*2 = 1024, 256 threads each, 4/CU
    const int grid = BC * HG * SPLIT;
    nms3d_kernel<<<grid, 256, 0, stream>>>(x, out);
}

// Round 2
// 237.055 us; speedup vs baseline: 1.0193x; 1.0193x over previous
//
#include <hip/hip_runtime.h>

// NMS3D (4,4,32,256,256) fp32, strict 26-neighbor max.
// R8: R7's d-rolling ring + COUNTED vmcnt (T4) instead of __syncthreads.
// R7 post-mortem: __syncthreads drains vmcnt(0) -> each step waited its OWN
// just-issued stage(d+2) DMAs (full HBM/L3 latency serialized x16 steps).
// Kernel was latency-bound: 95us, VALUBusy 12%, 2.4 TB/s. FETCH showed the
// input is L3-resident across iterations (89MB < 128MiB input), so read
// amplification is NOT the cost — pipeline structure is.
// Fix: raw s_barrier + s_waitcnt vmcnt(5). Per-wave VMEM FIFO at the wait:
//   [stage(d+1): 3 DMA] [2 nt-stores] [stage(d+2): 3 DMA]  = 8 outstanding
// vmcnt(5) retires exactly stage(d+1) (and possibly the cheap stores) while
// stage(d+2) stays in flight across the whole step -> one full step of slack
// per prefetch + 16 waves/CU of TLP. Staging padded to uniform 3 DMAs/wave
// (waves 2,3 duplicate row 9 with identical data) so the immediate is uniform.
// rule-#18 guards: sched_barrier(0) + memory-clobber asm fence the LDS reads.

typedef float v4f __attribute__((ext_vector_type(4)));

constexpr int W  = 256;
constexpr int H  = 256;
constexpr int D  = 32;
constexpr int SH = W;
constexpr int SD = W * H;
constexpr int HC = 8;               // h rows per block
constexpr int NR = HC + 2;          // 10 staged rows per plane
constexpr int NSLOT = 4;            // plane ring slots
constexpr int BC = 16;              // B*CH
constexpr int HG = H / HC;          // 32
constexpr int SPLIT = 2;            // d-range halves
constexpr int DR = D / SPLIT;       // 16 output planes per block
constexpr int PLW = NR * W;         // floats per plane slot

__device__ __forceinline__ v4f vmax4(v4f a, v4f b) {
    return (v4f){fmaxf(a.x, b.x), fmaxf(a.y, b.y), fmaxf(a.z, b.z), fmaxf(a.w, b.w)};
}

// Stage the 10 halo'd rows of logical plane p into ring slot p&3.
// UNIFORM 3 DMAs per wave (vmcnt immediates must be wave-uniform):
//   wave w -> rows {w, w+4, w+8}; rows 10,11 (waves 2,3) fold to row 9 with
//   the same source row -> identical-data duplicate write, benign.
__device__ __forceinline__ void stage_plane(const float* __restrict__ vol,
                                            float* lds, int p, int h0,
                                            int wv, int lane) {
    const int pc = p < 0 ? 0 : (p > D - 1 ? D - 1 : p);
    float* dst = lds + (p & 3) * PLW;
    const float* src = vol + pc * SD + (lane << 2);

    int h1 = h0 - 1 + wv;  h1 = h1 < 0 ? 0 : h1;           // wv<=3 -> no hi clamp
    const int h2 = h0 - 1 + wv + 4;                        // always in range
    int r3 = wv + 8;
    int h3 = h0 - 1 + r3;
    if (r3 > NR - 1) { r3 = NR - 1; h3 = h0 + 8; }         // waves 2,3: dup row 9
    h3 = h3 > H - 1 ? H - 1 : h3;

    __builtin_amdgcn_global_load_lds(
        (const __attribute__((address_space(1))) unsigned int*)(src + h1 * SH),
        (__attribute__((address_space(3))) unsigned int*)(dst + wv * W), 16, 0, 0);
    __builtin_amdgcn_global_load_lds(
        (const __attribute__((address_space(1))) unsigned int*)(src + h2 * SH),
        (__attribute__((address_space(3))) unsigned int*)(dst + (wv + 4) * W), 16, 0, 0);
    __builtin_amdgcn_global_load_lds(
        (const __attribute__((address_space(1))) unsigned int*)(src + h3 * SH),
        (__attribute__((address_space(3))) unsigned int*)(dst + r3 * W), 16, 0, 0);
}

// One output row from its 9 staged rows (3 h-rows x 3 planes). Verified math
// (absmax 0.0 in R6/R7): separable vertical max, shuffles for w-edges.
__device__ __forceinline__ v4f nms_row(v4f m0, v4f m1, v4f m2,
                                       v4f c0, v4f c1, v4f c2,
                                       v4f p0, v4f p1, v4f p2,
                                       bool valid, int lane) {
    const v4f a3m = vmax4(vmax4(m0, m1), m2);   // plane d-1, all 3 rows
    const v4f a3p = vmax4(vmax4(p0, p1), p2);   // plane d+1, all 3 rows
    const v4f a20 = vmax4(c0, c2);              // plane d, h +- 1
    const v4f v8  = vmax4(vmax4(a3m, a3p), a20);
    const v4f c   = c1;

    const float l8 = __shfl_up(v8.w, 1);     // lane0 garbage, masked below
    const float r8 = __shfl_down(v8.x, 1);   // lane63 garbage, masked below
    const float lc = __shfl_up(c.w, 1);
    const float rc = __shfl_down(c.x, 1);

    float n0 = fmaxf(fmaxf(l8,   v8.x), v8.y);
    float n1 = fmaxf(fmaxf(v8.x, v8.y), v8.z);
    float n2 = fmaxf(fmaxf(v8.y, v8.z), v8.w);
    float n3 = fmaxf(fmaxf(v8.z, v8.w), r8);
    n0 = fmaxf(n0, fmaxf(lc,  c.y));
    n1 = fmaxf(n1, fmaxf(c.x, c.z));
    n2 = fmaxf(n2, fmaxf(c.y, c.w));
    n3 = fmaxf(n3, fmaxf(c.z, rc));

    v4f o;
    o.x = (valid && lane > 0  && c.x > n0) ? c.x : 0.f;
    o.y = (valid && c.y > n1) ? c.y : 0.f;
    o.z = (valid && c.z > n2) ? c.z : 0.f;
    o.w = (valid && lane < 63 && c.w > n3) ? c.w : 0.f;
    return o;
}

__global__ __launch_bounds__(256, 4) void nms3d_kernel(const float* __restrict__ x,
                                                       float* __restrict__ out) {
    __shared__ float lds[NSLOT * PLW];   // 40 KiB -> 4 blocks/CU

    const int blk  = blockIdx.x;
    const int wv   = threadIdx.x >> 6;   // 0..3
    const int lane = threadIdx.x & 63;
    const int hc   = blk & (HG - 1);           // fastest: h-neighbors share halo rows in L2/L3
    const int half = (blk >> 5) & (SPLIT - 1);
    const int bc   = blk >> 6;
    const int d0   = half * DR;
    const int h0   = hc * HC;

    const float* vol  = x   + bc * (D * SD);
    float*       ovol = out + bc * (D * SD);

    // ---- prologue: stage planes d0-1, d0, d0+1; full drain once ----
    stage_plane(vol, lds, d0 - 1, h0, wv, lane);
    stage_plane(vol, lds, d0,     h0, wv, lane);
    stage_plane(vol, lds, d0 + 1, h0, wv, lane);
    __syncthreads();   // vmcnt(0) drain + barrier: 3 planes resident, FIFO empty

    const int i0 = wv * 2;               // this wave's two output rows (i0, i0+1)
    const int h  = h0 + i0;
    const bool hv0 = (h > 0) && (h < H - 1);        // wave-uniform
    const bool hv1 = (h + 1 < H - 1);               // h+1 > 0 always

    #pragma unroll 1
    for (int d = d0; d < d0 + DR; ++d) {
        // issue prefetch of plane d+2 into slot (d-2)&3 (retired by last step's
        // end barrier). Stays IN FLIGHT across this whole step: the counted
        // wait below never touches it.
        stage_plane(vol, lds, d + 2, h0, wv, lane);
        __builtin_amdgcn_sched_barrier(0);          // pin DMA issue above the wait

        // Per-wave VMEM FIFO here (oldest->newest):
        //   stage(d+1) [3] , nt-stores of step d-1 [2] , stage(d+2) [3] = 8.
        // vmcnt(5) -> stage(d+1) retired (LDS data visible), stage(d+2) in flight.
        asm volatile("s_waitcnt vmcnt(5)" ::: "memory");
        __builtin_amdgcn_s_barrier();               // all waves' stage(d+1) done
        asm volatile("" ::: "memory");
        __builtin_amdgcn_sched_barrier(0);          // no LDS-read hoist above this

        const bool dv = (d > 0) && (d < D - 1);
        const float* Lm = lds + ((d - 1) & 3) * PLW + i0 * W + (lane << 2);
        const float* L0 = lds + ( d      & 3) * PLW + i0 * W + (lane << 2);
        const float* Lp = lds + ((d + 1) & 3) * PLW + i0 * W + (lane << 2);

        // rows i0..i0+3 of each plane feed output rows i0, i0+1
        const v4f m0 = *(const v4f*)(Lm + 0 * W), m1 = *(const v4f*)(Lm + 1 * W);
        const v4f m2 = *(const v4f*)(Lm + 2 * W), m3 = *(const v4f*)(Lm + 3 * W);
        const v4f c0 = *(const v4f*)(L0 + 0 * W), c1 = *(const v4f*)(L0 + 1 * W);
        const v4f c2 = *(const v4f*)(L0 + 2 * W), c3 = *(const v4f*)(L0 + 3 * W);
        const v4f p0 = *(const v4f*)(Lp + 0 * W), p1 = *(const v4f*)(Lp + 1 * W);
        const v4f p2 = *(const v4f*)(Lp + 2 * W), p3 = *(const v4f*)(Lp + 3 * W);

        float* orow = ovol + d * SD + h * SH + (lane << 2);
        const v4f o0 = nms_row(m0, m1, m2, c0, c1, c2, p0, p1, p2, hv0 && dv, lane);
        __builtin_nontemporal_store(o0, (v4f*)orow);
        const v4f o1 = nms_row(m1, m2, m3, c1, c2, c3, p1, p2, p3, hv1 && dv, lane);
        __builtin_nontemporal_store(o1, (v4f*)(orow + SH));

        // WAR guard: slot (d-1)&3 is overwritten by NEXT step's stage(d+3).
        // This barrier keeps any wave from issuing that DMA while a slower
        // wave still reads plane d-1 above. Raw barrier: NO vmcnt drain.
        __builtin_amdgcn_sched_barrier(0);
        asm volatile("" ::: "memory");
        __builtin_amdgcn_s_barrier();
    }
}

extern "C" void kernel_launch(void* const* d_in, const int* in_sizes, int n_in,
                              void* d_out, int out_size, void* d_ws, size_t ws_size,
                              hipStream_t stream) {
    const float* x = (const float*)d_in[0];
    float* out = (float*)d_out;
    // blocks = BC * HG * SPLIT = 16*32*2 = 1024, 256 threads each, 4/CU
    const int grid = BC * HG * SPLIT;
    nms3d_kernel<<<grid, 256, 0, stream>>>(x, out);
}

// Round 3
// 222.813 us; speedup vs baseline: 1.0844x; 1.0639x over previous
//
#include <hip/hip_runtime.h>

// NMS3D (4,4,32,256,256) fp32, strict 26-neighbor max.
// R9: back to R6's independent-block shape (stage -> one sync -> compute),
// with SMALLER tiles for occupancy + turnover.
// R7/R8 post-mortem: persistent d-rolling blocks (1024 = exactly 4/CU, zero
// turnover) were barrier-convergence-bound: 16 lock-step steps x 2 barriers,
// VALUBusy 13%, occ 34%, 85us — worse than R6's dumb independent blocks
// (~65us slice). FETCH=89MB (< input) proved reads are L3-resident, so the
// read-amp that R7/R8 optimized was never the binding resource.
// R9: KD=4, HC=4 -> staged tile 6 planes x 6 rows = 36 KiB LDS
//   -> 4 blocks/CU (16 waves, was 2 blocks/8 waves in R6), 8192 blocks,
//      32 sequenced per CU: one block's DMA drain hides under neighbors'
//      compute. Read amp 2.25x (vs R6 1.875x) — absorbed by L3.
// Staging stays fire-and-forget global_load_lds DMA (R1-R5: register
// pipelines get de-pipelined by the compiler). Math verified (absmax 0.0
// in R6/R7/R8): separable vertical max + lane shuffles for w-edges.

typedef float v4f __attribute__((ext_vector_type(4)));

constexpr int W  = 256;
constexpr int H  = 256;
constexpr int D  = 32;
constexpr int SH = W;
constexpr int SD = W * H;
constexpr int KD = 4;                  // d outputs per block (1 per wave)
constexpr int HC = 4;                  // h rows per block
constexpr int BC = 16;                 // B*CH
constexpr int DG = D / KD;             // 8
constexpr int HG = H / HC;             // 64
constexpr int NPL = KD + 2;            // 6 staged planes
constexpr int NR  = HC + 2;            // 6 staged rows per plane
constexpr int TROWS = NPL * NR;        // 36 rows of W floats = 36 KiB

__device__ __forceinline__ v4f vmax4(v4f a, v4f b) {
    return (v4f){fmaxf(a.x, b.x), fmaxf(a.y, b.y), fmaxf(a.z, b.z), fmaxf(a.w, b.w)};
}

__global__ __launch_bounds__(256, 4) void nms3d_kernel(const float* __restrict__ x,
                                                       float* __restrict__ out) {
    __shared__ float lds[TROWS * W];   // 36 KiB -> 4 blocks/CU

    const int blk  = blockIdx.x;
    const int wv   = threadIdx.x >> 6;   // 0..3
    const int lane = threadIdx.x & 63;
    const int hc   = blk & (HG - 1);            // fastest: h-neighbors share halo in L2
    const int dg   = (blk >> 6) & (DG - 1);
    const int bc   = blk >> 9;
    const int d0   = dg * KD;
    const int h0   = hc * HC;

    const float* vol = x + bc * (D * SD);

    // ---- stage 36 rows; wave wv stages flat rows t = wv*9 .. wv*9+8 ----
    #pragma unroll
    for (int u = 0; u < TROWS / 4; ++u) {       // 9 DMA instrs per wave
        const int t = wv * (TROWS / 4) + u;
        const int j = t / NR;
        const int r = t - j * NR;
        int p = d0 - 1 + j;  p = p < 0 ? 0 : (p > D - 1 ? D - 1 : p);
        int hh = h0 - 1 + r; hh = hh < 0 ? 0 : (hh > H - 1 ? H - 1 : hh);
        const float* gp = vol + p * SD + hh * SH + (lane << 2);
        // lane i's 16B land at ldsbase + 16*i -> exactly row-major row layout
        __builtin_amdgcn_global_load_lds(
            (const __attribute__((address_space(1))) unsigned int*)gp,
            (__attribute__((address_space(3))) unsigned int*)&lds[(j * NR + r) * W],
            16, 0, 0);
    }
    __syncthreads();   // drains vmcnt (DMA) then barrier — the block's only sync

    // ---- compute: wave wv handles output plane d = d0 + wv ----
    const int d = d0 + wv;
    const bool dv = (d > 0) && (d < D - 1);
    float* ovol = out + bc * (D * SD) + d * SD + (lane << 2);

    const float* Lm = lds + (wv * NR) * W + (lane << 2);        // plane d-1
    const float* L0 = lds + ((wv + 1) * NR) * W + (lane << 2);  // plane d
    const float* Lp = lds + ((wv + 2) * NR) * W + (lane << 2);  // plane d+1

    // rolling 3-row window per plane, slot = (row mod 3), fully unrolled
    v4f rm[3], r0[3], rp[3];
    rm[0] = *(const v4f*)(Lm + 0 * W); r0[0] = *(const v4f*)(L0 + 0 * W); rp[0] = *(const v4f*)(Lp + 0 * W);
    rm[1] = *(const v4f*)(Lm + 1 * W); r0[1] = *(const v4f*)(L0 + 1 * W); rp[1] = *(const v4f*)(Lp + 1 * W);

    #pragma unroll
    for (int i = 0; i < HC; ++i) {
        const int s0 = i % 3, s1 = (i + 1) % 3, s2 = (i + 2) % 3;
        rm[s2] = *(const v4f*)(Lm + (i + 2) * W);
        r0[s2] = *(const v4f*)(L0 + (i + 2) * W);
        rp[s2] = *(const v4f*)(Lp + (i + 2) * W);

        // separable: per-plane maxes over the 3 h-rows
        const v4f a3m = vmax4(vmax4(rm[s0], rm[s1]), rm[s2]);   // plane d-1, all rows
        const v4f a3p = vmax4(vmax4(rp[s0], rp[s1]), rp[s2]);   // plane d+1, all rows
        const v4f a20 = vmax4(r0[s0], r0[s2]);                  // plane d, h +- 1
        const v4f v8  = vmax4(vmax4(a3m, a3p), a20);            // 8 non-center rows
        const v4f c   = r0[s1];

        const float l8 = __shfl_up(v8.w, 1);     // lane0 garbage, masked
        const float r8 = __shfl_down(v8.x, 1);   // lane63 garbage, masked
        const float lc = __shfl_up(c.w, 1);
        const float rc = __shfl_down(c.x, 1);

        float n0 = fmaxf(fmaxf(l8,   v8.x), v8.y);
        float n1 = fmaxf(fmaxf(v8.x, v8.y), v8.z);
        float n2 = fmaxf(fmaxf(v8.y, v8.z), v8.w);
        float n3 = fmaxf(fmaxf(v8.z, v8.w), r8);
        n0 = fmaxf(n0, fmaxf(lc,  c.y));
        n1 = fmaxf(n1, fmaxf(c.x, c.z));
        n2 = fmaxf(n2, fmaxf(c.y, c.w));
        n3 = fmaxf(n3, fmaxf(c.z, rc));

        const int h = h0 + i;
        const bool hv = (h > 0) && (h < H - 1);   // wave-uniform
        const bool v  = hv && dv;
        v4f o;
        o.x = (v && lane > 0  && c.x > n0) ? c.x : 0.f;
        o.y = (v && c.y > n1) ? c.y : 0.f;
        o.z = (v && c.z > n2) ? c.z : 0.f;
        o.w = (v && lane < 63 && c.w > n3) ? c.w : 0.f;
        __builtin_nontemporal_store(o, (v4f*)(ovol + h * SH));
    }
}

extern "C" void kernel_launch(void* const* d_in, const int* in_sizes, int n_in,
                              void* d_out, int out_size, void* d_ws, size_t ws_size,
                              hipStream_t stream) {
    const float* x = (const float*)d_in[0];
    float* out = (float*)d_out;
    // blocks = BC * DG * HG = 16*8*64 = 8192, 256 threads each, 4 blocks/CU
    const int grid = BC * DG * HG;
    nms3d_kernel<<<grid, 256, 0, stream>>>(x, out);
}